// Round 1
// baseline (1086.990 us; speedup 1.0000x reference)
//
#include <hip/hip_runtime.h>
#include <hip/hip_bf16.h>
#include <stdint.h>

#define D_DIM 1024
#define E_NUM 8
#define H_DIM 4096

typedef __attribute__((ext_vector_type(8))) short short8;
typedef __attribute__((ext_vector_type(4))) float f32x4;

#define GLOBAL_AS __attribute__((address_space(1)))
#define LDS_AS __attribute__((address_space(3)))

__device__ __forceinline__ void async_load16(const void* g, void* l) {
    __builtin_amdgcn_global_load_lds((GLOBAL_AS void*)g, (LDS_AS void*)l, 16, 0, 0);
}

__device__ __forceinline__ float gelu_exact(float v) {
    return 0.5f * v * (1.0f + erff(v * 0.70710678118654752f));
}

// ---------------- router: logits (fp64), softmax, top-2, bucket append; fused x->bf16 ----------------
__global__ __launch_bounds__(256) void router_kernel(
    const float* __restrict__ x, const float* __restrict__ Wg,
    __hip_bfloat16* __restrict__ xb, int* __restrict__ cnt,
    int* __restrict__ tok, float* __restrict__ wgt, int T) {
    int gwave = (int)((blockIdx.x * 256 + threadIdx.x) >> 6);
    int lane = threadIdx.x & 63;
    if (gwave >= T) return;
    const float* xr = x + (size_t)gwave * D_DIM;
    double acc[E_NUM];
#pragma unroll
    for (int e = 0; e < E_NUM; ++e) acc[e] = 0.0;
#pragma unroll
    for (int i = 0; i < D_DIM / 64; ++i) {
        int d = i * 64 + lane;
        float xv = xr[d];
        xb[(size_t)gwave * D_DIM + d] = __float2bfloat16(xv);
        const float4* wgp = (const float4*)(Wg + (size_t)d * E_NUM);
        float4 wa = wgp[0], wb = wgp[1];
        double xd = (double)xv;
        acc[0] += xd * (double)wa.x; acc[1] += xd * (double)wa.y;
        acc[2] += xd * (double)wa.z; acc[3] += xd * (double)wa.w;
        acc[4] += xd * (double)wb.x; acc[5] += xd * (double)wb.y;
        acc[6] += xd * (double)wb.z; acc[7] += xd * (double)wb.w;
    }
#pragma unroll
    for (int s = 32; s > 0; s >>= 1) {
#pragma unroll
        for (int e = 0; e < E_NUM; ++e) acc[e] += __shfl_xor(acc[e], s);
    }
    double mx = acc[0];
#pragma unroll
    for (int e = 1; e < E_NUM; ++e) mx = fmax(mx, acc[e]);
    double p[E_NUM]; double sum = 0.0;
#pragma unroll
    for (int e = 0; e < E_NUM; ++e) { p[e] = exp(acc[e] - mx); sum += p[e]; }
    int i0 = 0;
#pragma unroll
    for (int e = 1; e < E_NUM; ++e) if (p[e] > p[i0]) i0 = e;
    int i1 = (i0 == 0) ? 1 : 0;
#pragma unroll
    for (int e = 0; e < E_NUM; ++e) if (e != i0 && p[e] > p[i1]) i1 = e;
    float w0 = (float)(p[i0] / sum);
    float w1 = (float)(p[i1] / sum);
    if (lane == 0) {
        int s0 = atomicAdd(&cnt[i0], 1);
        tok[i0 * T + s0] = gwave; wgt[i0 * T + s0] = w0;
        int s1 = atomicAdd(&cnt[i1], 1);
        tok[i1 * T + s1] = gwave; wgt[i1 * T + s1] = w1;
    }
}

__global__ void prefix_kernel(const int* __restrict__ cnt, int* __restrict__ base) {
    if (threadIdx.x == 0) {
        int a = 0;
#pragma unroll
        for (int e = 0; e < E_NUM; ++e) { base[e] = a; a += cnt[e]; }
    }
}

// ---------------- transpose + fp32->bf16: in [E][R][C] f32 -> out [E][C][R] bf16 ----------------
__global__ __launch_bounds__(256) void transpose_conv_kernel(
    const float* __restrict__ in, __hip_bfloat16* __restrict__ out, int R, int C) {
    __shared__ float tile[32][33];
    int e = blockIdx.z;
    int c0 = blockIdx.x * 32, r0 = blockIdx.y * 32;
    const float* ip = in + (size_t)e * R * C;
    __hip_bfloat16* op = out + (size_t)e * C * R;
    int tx = threadIdx.x, ty = threadIdx.y;
#pragma unroll
    for (int i = 0; i < 32; i += 8)
        tile[ty + i][tx] = ip[(size_t)(r0 + ty + i) * C + (c0 + tx)];
    __syncthreads();
#pragma unroll
    for (int i = 0; i < 32; i += 8)
        op[(size_t)(c0 + ty + i) * R + (r0 + tx)] = __float2bfloat16(tile[tx][ty + i]);
}

// ---------------- GEMM1: h[slot,:] = gelu(x[tok] @ W1[e] + b1[e]), bf16 MFMA, gathered A ----------------
__global__ __launch_bounds__(256) void gemm1_kernel(
    const __hip_bfloat16* __restrict__ xb,   // [T][D]
    const __hip_bfloat16* __restrict__ w1t,  // [E][H][D] (B^T layout)
    const float* __restrict__ b1,            // [E][H]
    const int* __restrict__ cnt, const int* __restrict__ base,
    const int* __restrict__ tok,
    __hip_bfloat16* __restrict__ hbuf,       // [2T][H]
    int T) {
    int e = blockIdx.z;
    int M = cnt[e];
    int m0 = blockIdx.y * 128;
    if (m0 >= M) return;
    int n0 = blockIdx.x * 128;
    const __hip_bfloat16* Bp = w1t + (size_t)e * H_DIM * D_DIM;

    __shared__ __align__(16) short sA[128 * 32];
    __shared__ __align__(16) short sB[128 * 32];
    char* sAc = (char*)sA; char* sBc = (char*)sB;

    int tid = threadIdx.x;
    int w = tid >> 6, lane = tid & 63;
    int wm = w >> 1, wn = w & 1;
    int q = lane >> 4, l4 = lane & 15;

    int o0 = w * 2048 + lane * 16;
    int o1 = o0 + 1024;
    int r0 = o0 >> 6, k0b = (o0 & 63) >> 1;
    int r1 = o1 >> 6, k1b = (o1 & 63) >> 1;
    int tA0 = tok[e * T + min(m0 + r0, M - 1)];
    int tA1 = tok[e * T + min(m0 + r1, M - 1)];
    const __hip_bfloat16* gA0 = xb + (size_t)tA0 * D_DIM + k0b;
    const __hip_bfloat16* gA1 = xb + (size_t)tA1 * D_DIM + k1b;
    const __hip_bfloat16* gB0 = Bp + (size_t)(n0 + r0) * D_DIM + k0b;
    const __hip_bfloat16* gB1 = Bp + (size_t)(n0 + r1) * D_DIM + k1b;
    char* lA0 = sAc + w * 2048; char* lA1 = lA0 + 1024;
    char* lB0 = sBc + w * 2048; char* lB1 = lB0 + 1024;

    f32x4 acc[4][4];
#pragma unroll
    for (int a = 0; a < 4; ++a)
#pragma unroll
        for (int b = 0; b < 4; ++b) acc[a][b] = (f32x4){0.f, 0.f, 0.f, 0.f};

    for (int kk = 0; kk < D_DIM; kk += 32) {
        async_load16(gA0 + kk, lA0);
        async_load16(gA1 + kk, lA1);
        async_load16(gB0 + kk, lB0);
        async_load16(gB1 + kk, lB1);
        __syncthreads();
        short8 aF[4], bF[4];
#pragma unroll
        for (int t = 0; t < 4; ++t) {
            int ra = wm * 64 + t * 16 + l4;
            aF[t] = *(const short8*)(sAc + ra * 64 + q * 16);
            int rb = wn * 64 + t * 16 + l4;
            bF[t] = *(const short8*)(sBc + rb * 64 + q * 16);
        }
#pragma unroll
        for (int tm = 0; tm < 4; ++tm)
#pragma unroll
            for (int tn = 0; tn < 4; ++tn)
                acc[tm][tn] = __builtin_amdgcn_mfma_f32_16x16x32_bf16(aF[tm], bF[tn], acc[tm][tn], 0, 0, 0);
        __syncthreads();
    }

    int sb = base[e];
#pragma unroll
    for (int tm = 0; tm < 4; ++tm) {
        int rbase = wm * 64 + tm * 16 + q * 4;
#pragma unroll
        for (int i = 0; i < 4; ++i) {
            int row = m0 + rbase + i;
            if (row < M) {
                size_t hrow = (size_t)(sb + row) * H_DIM;
#pragma unroll
                for (int tn = 0; tn < 4; ++tn) {
                    int col = n0 + wn * 64 + tn * 16 + l4;
                    float v = acc[tm][tn][i] + b1[e * H_DIM + col];
                    hbuf[hrow + col] = __float2bfloat16(gelu_exact(v));
                }
            }
        }
    }
}

// ---------------- GEMM2: out[tok,:] += w * (h @ W2[e] + b2[e]) ----------------
__global__ __launch_bounds__(256) void gemm2_kernel(
    const __hip_bfloat16* __restrict__ hbuf, // [2T][H]
    const __hip_bfloat16* __restrict__ w2t,  // [E][D][H] (B^T layout)
    const float* __restrict__ b2,            // [E][D]
    const int* __restrict__ cnt, const int* __restrict__ base,
    const int* __restrict__ tok, const float* __restrict__ wgt,
    float* __restrict__ out, int T) {
    int e = blockIdx.z;
    int M = cnt[e];
    int m0 = blockIdx.y * 128;
    if (m0 >= M) return;
    int n0 = blockIdx.x * 128;
    int sb = base[e];
    const __hip_bfloat16* Bp = w2t + (size_t)e * D_DIM * H_DIM;

    __shared__ __align__(16) short sA[128 * 32];
    __shared__ __align__(16) short sB[128 * 32];
    char* sAc = (char*)sA; char* sBc = (char*)sB;

    int tid = threadIdx.x;
    int w = tid >> 6, lane = tid & 63;
    int wm = w >> 1, wn = w & 1;
    int q = lane >> 4, l4 = lane & 15;

    int o0 = w * 2048 + lane * 16;
    int o1 = o0 + 1024;
    int r0 = o0 >> 6, k0b = (o0 & 63) >> 1;
    int r1 = o1 >> 6, k1b = (o1 & 63) >> 1;
    const __hip_bfloat16* gA0 = hbuf + (size_t)(sb + min(m0 + r0, M - 1)) * H_DIM + k0b;
    const __hip_bfloat16* gA1 = hbuf + (size_t)(sb + min(m0 + r1, M - 1)) * H_DIM + k1b;
    const __hip_bfloat16* gB0 = Bp + (size_t)(n0 + r0) * H_DIM + k0b;
    const __hip_bfloat16* gB1 = Bp + (size_t)(n0 + r1) * H_DIM + k1b;
    char* lA0 = sAc + w * 2048; char* lA1 = lA0 + 1024;
    char* lB0 = sBc + w * 2048; char* lB1 = lB0 + 1024;

    f32x4 acc[4][4];
#pragma unroll
    for (int a = 0; a < 4; ++a)
#pragma unroll
        for (int b = 0; b < 4; ++b) acc[a][b] = (f32x4){0.f, 0.f, 0.f, 0.f};

    for (int kk = 0; kk < H_DIM; kk += 32) {
        async_load16(gA0 + kk, lA0);
        async_load16(gA1 + kk, lA1);
        async_load16(gB0 + kk, lB0);
        async_load16(gB1 + kk, lB1);
        __syncthreads();
        short8 aF[4], bF[4];
#pragma unroll
        for (int t = 0; t < 4; ++t) {
            int ra = wm * 64 + t * 16 + l4;
            aF[t] = *(const short8*)(sAc + ra * 64 + q * 16);
            int rb = wn * 64 + t * 16 + l4;
            bF[t] = *(const short8*)(sBc + rb * 64 + q * 16);
        }
#pragma unroll
        for (int tm = 0; tm < 4; ++tm)
#pragma unroll
            for (int tn = 0; tn < 4; ++tn)
                acc[tm][tn] = __builtin_amdgcn_mfma_f32_16x16x32_bf16(aF[tm], bF[tn], acc[tm][tn], 0, 0, 0);
        __syncthreads();
    }

#pragma unroll
    for (int tm = 0; tm < 4; ++tm) {
        int rbase = wm * 64 + tm * 16 + q * 4;
#pragma unroll
        for (int i = 0; i < 4; ++i) {
            int row = m0 + rbase + i;
            if (row < M) {
                int tk = tok[e * T + row];
                float wv = wgt[e * T + row];
                float* orow = out + (size_t)tk * D_DIM;
#pragma unroll
                for (int tn = 0; tn < 4; ++tn) {
                    int col = n0 + wn * 64 + tn * 16 + l4;
                    float v = acc[tm][tn][i] + b2[e * D_DIM + col];
                    atomicAdd(&orow[col], wv * v);
                }
            }
        }
    }
}

extern "C" void kernel_launch(void* const* d_in, const int* in_sizes, int n_in,
                              void* d_out, int out_size, void* d_ws, size_t ws_size,
                              hipStream_t stream) {
    const float* x  = (const float*)d_in[0];
    const float* Wg = (const float*)d_in[1];
    const float* W1 = (const float*)d_in[2];
    const float* b1 = (const float*)d_in[3];
    const float* W2 = (const float*)d_in[4];
    const float* b2 = (const float*)d_in[5];
    int T = in_sizes[0] / D_DIM;  // 8192

    char* p = (char*)d_ws;
    int* cnt   = (int*)p;
    int* base  = (int*)(p + 256);
    int* tok   = (int*)(p + 512);
    float* wgt = (float*)(p + 512 + 4ll * E_NUM * T);
    char* pb = p + 512 + 8ll * E_NUM * T;
    __hip_bfloat16* xb  = (__hip_bfloat16*)pb;
    __hip_bfloat16* w1t = (__hip_bfloat16*)(pb + 2ll * T * D_DIM);
    __hip_bfloat16* w2t = (__hip_bfloat16*)(pb + 2ll * T * D_DIM + 2ll * E_NUM * H_DIM * D_DIM);
    __hip_bfloat16* hb  = (__hip_bfloat16*)(pb + 2ll * T * D_DIM + 4ll * E_NUM * H_DIM * D_DIM);

    hipMemsetAsync(cnt, 0, E_NUM * sizeof(int), stream);
    hipMemsetAsync(d_out, 0, (size_t)out_size * sizeof(float), stream);

    router_kernel<<<dim3((T + 3) / 4), 256, 0, stream>>>(x, Wg, xb, cnt, tok, wgt, T);
    prefix_kernel<<<1, 64, 0, stream>>>(cnt, base);
    transpose_conv_kernel<<<dim3(H_DIM / 32, D_DIM / 32, E_NUM), dim3(32, 8), 0, stream>>>(W1, w1t, D_DIM, H_DIM);
    transpose_conv_kernel<<<dim3(D_DIM / 32, H_DIM / 32, E_NUM), dim3(32, 8), 0, stream>>>(W2, w2t, H_DIM, D_DIM);
    gemm1_kernel<<<dim3(H_DIM / 128, T / 128, E_NUM), 256, 0, stream>>>(xb, w1t, b1, cnt, base, tok, hb, T);
    gemm2_kernel<<<dim3(D_DIM / 128, T / 128, E_NUM), 256, 0, stream>>>(hb, w2t, b2, cnt, base, tok, wgt, (float*)d_out, T);
}

// Round 2
// 984.468 us; speedup vs baseline: 1.1041x; 1.1041x over previous
//
#include <hip/hip_runtime.h>
#include <hip/hip_bf16.h>
#include <stdint.h>

#define D_DIM 1024
#define E_NUM 8
#define H_DIM 4096

typedef __attribute__((ext_vector_type(8))) short short8;
typedef __attribute__((ext_vector_type(4))) short short4v;
typedef __attribute__((ext_vector_type(4))) float f32x4;

#define GLOBAL_AS __attribute__((address_space(1)))
#define LDS_AS __attribute__((address_space(3)))

__device__ __forceinline__ void async_load16(const void* g, void* l) {
    __builtin_amdgcn_global_load_lds((GLOBAL_AS void*)g, (LDS_AS void*)l, 16, 0, 0);
}

__device__ __forceinline__ float gelu_exact(float v) {
    return 0.5f * v * (1.0f + erff(v * 0.70710678118654752f));
}

__device__ __forceinline__ float b2f(short s) {
    union { float f; unsigned u; } x; x.u = ((unsigned)(unsigned short)s) << 16; return x.f;
}

// ---------------- router: logits (fp64), softmax, top-2, bucket append; fused x->bf16 ----------------
__global__ __launch_bounds__(256) void router_kernel(
    const float* __restrict__ x, const float* __restrict__ Wg,
    __hip_bfloat16* __restrict__ xb, int* __restrict__ cnt,
    int* __restrict__ tok, int* __restrict__ eidx, float* __restrict__ ewgt, int T) {
    int gwave = (int)((blockIdx.x * 256 + threadIdx.x) >> 6);
    int lane = threadIdx.x & 63;
    if (gwave >= T) return;
    const float* xr = x + (size_t)gwave * D_DIM;
    double acc[E_NUM];
#pragma unroll
    for (int e = 0; e < E_NUM; ++e) acc[e] = 0.0;
#pragma unroll
    for (int i = 0; i < D_DIM / 64; ++i) {
        int d = i * 64 + lane;
        float xv = xr[d];
        xb[(size_t)gwave * D_DIM + d] = __float2bfloat16(xv);
        const float4* wgp = (const float4*)(Wg + (size_t)d * E_NUM);
        float4 wa = wgp[0], wb = wgp[1];
        double xd = (double)xv;
        acc[0] += xd * (double)wa.x; acc[1] += xd * (double)wa.y;
        acc[2] += xd * (double)wa.z; acc[3] += xd * (double)wa.w;
        acc[4] += xd * (double)wb.x; acc[5] += xd * (double)wb.y;
        acc[6] += xd * (double)wb.z; acc[7] += xd * (double)wb.w;
    }
#pragma unroll
    for (int s = 32; s > 0; s >>= 1) {
#pragma unroll
        for (int e = 0; e < E_NUM; ++e) acc[e] += __shfl_xor(acc[e], s);
    }
    double mx = acc[0];
#pragma unroll
    for (int e = 1; e < E_NUM; ++e) mx = fmax(mx, acc[e]);
    double p[E_NUM]; double sum = 0.0;
#pragma unroll
    for (int e = 0; e < E_NUM; ++e) { p[e] = exp(acc[e] - mx); sum += p[e]; }
    int i0 = 0;
#pragma unroll
    for (int e = 1; e < E_NUM; ++e) if (p[e] > p[i0]) i0 = e;
    int i1 = (i0 == 0) ? 1 : 0;
#pragma unroll
    for (int e = 0; e < E_NUM; ++e) if (e != i0 && p[e] > p[i1]) i1 = e;
    float w0 = (float)(p[i0] / sum);
    float w1 = (float)(p[i1] / sum);
    if (lane == 0) {
        int s0 = atomicAdd(&cnt[i0], 1);
        tok[i0 * T + s0] = gwave;
        eidx[2 * gwave]     = (i0 << 16) | s0;
        ewgt[2 * gwave]     = w0;
        int s1 = atomicAdd(&cnt[i1], 1);
        tok[i1 * T + s1] = gwave;
        eidx[2 * gwave + 1] = (i1 << 16) | s1;
        ewgt[2 * gwave + 1] = w1;
    }
}

__global__ void prefix_kernel(const int* __restrict__ cnt, int* __restrict__ base) {
    if (threadIdx.x == 0) {
        int a = 0;
#pragma unroll
        for (int e = 0; e < E_NUM; ++e) { base[e] = a; a += cnt[e]; }
    }
}

// ---------------- transpose + fp32->bf16: in [E][R][C] f32 -> out [E][C][R] bf16 ----------------
__global__ __launch_bounds__(256) void transpose_conv_kernel(
    const float* __restrict__ in, __hip_bfloat16* __restrict__ out, int R, int C) {
    __shared__ float tile[32][33];
    int e = blockIdx.z;
    int c0 = blockIdx.x * 32, r0 = blockIdx.y * 32;
    const float* ip = in + (size_t)e * R * C;
    __hip_bfloat16* op = out + (size_t)e * C * R;
    int tx = threadIdx.x, ty = threadIdx.y;
#pragma unroll
    for (int i = 0; i < 32; i += 8)
        tile[ty + i][tx] = ip[(size_t)(r0 + ty + i) * C + (c0 + tx)];
    __syncthreads();
#pragma unroll
    for (int i = 0; i < 32; i += 8)
        op[(size_t)(c0 + ty + i) * R + (r0 + tx)] = __float2bfloat16(tile[tx][ty + i]);
}

// LDS layout swizzle: row r, 16B-chunk k stored at chunk index r*4 + (k ^ ((r>>1)&3)).
// Writer side (async load, dest fixed at base+lane*16): lane sources global
// row = seg*16 + (lane>>2), chunk k = (lane&3) ^ ((lane>>3)&3).
// Reader side: chunk q of row ra at byte offset ra*64 + ((q ^ ((ra>>1)&3))<<4).
// This makes the 16-lane ds_read_b128 hit all 8 bank groups twice (free 2-way).

// ---------------- GEMM1: h[slot,:] = gelu(x[tok] @ W1[e] + b1[e]) ----------------
__global__ __launch_bounds__(256) void gemm1_kernel(
    const __hip_bfloat16* __restrict__ xb,   // [T][D]
    const __hip_bfloat16* __restrict__ w1t,  // [E][H][D] (B^T layout)
    const float* __restrict__ b1,            // [E][H]
    const int* __restrict__ cnt, const int* __restrict__ base,
    const int* __restrict__ tok,
    __hip_bfloat16* __restrict__ hbuf,       // [2T][H]
    int T) {
    int e = blockIdx.z;
    int M = cnt[e];
    int m0 = blockIdx.y * 128;
    if (m0 >= M) return;
    int n0 = blockIdx.x * 128;
    const __hip_bfloat16* Bp = w1t + (size_t)e * H_DIM * D_DIM;

    __shared__ __align__(16) short sA[128 * 32];
    __shared__ __align__(16) short sB[128 * 32];
    char* sAc = (char*)sA; char* sBc = (char*)sB;

    int tid = threadIdx.x;
    int w = tid >> 6, lane = tid & 63;
    int wm = w >> 1, wn = w & 1;
    int q = lane >> 4, l4 = lane & 15;

    int kswz = ((lane & 3) ^ ((lane >> 3) & 3)) << 3;  // swizzled element offset
    int r0 = w * 32 + (lane >> 2);
    int r1 = r0 + 16;
    int tA0 = tok[e * T + min(m0 + r0, M - 1)];
    int tA1 = tok[e * T + min(m0 + r1, M - 1)];
    const __hip_bfloat16* gA0 = xb + (size_t)tA0 * D_DIM + kswz;
    const __hip_bfloat16* gA1 = xb + (size_t)tA1 * D_DIM + kswz;
    const __hip_bfloat16* gB0 = Bp + (size_t)(n0 + r0) * D_DIM + kswz;
    const __hip_bfloat16* gB1 = Bp + (size_t)(n0 + r1) * D_DIM + kswz;
    char* lA0 = sAc + w * 2048; char* lA1 = lA0 + 1024;
    char* lB0 = sBc + w * 2048; char* lB1 = lB0 + 1024;

    f32x4 acc[4][4];
#pragma unroll
    for (int a = 0; a < 4; ++a)
#pragma unroll
        for (int b = 0; b < 4; ++b) acc[a][b] = (f32x4){0.f, 0.f, 0.f, 0.f};

    for (int kk = 0; kk < D_DIM; kk += 32) {
        async_load16(gA0 + kk, lA0);
        async_load16(gA1 + kk, lA1);
        async_load16(gB0 + kk, lB0);
        async_load16(gB1 + kk, lB1);
        __syncthreads();
        short8 aF[4], bF[4];
#pragma unroll
        for (int t = 0; t < 4; ++t) {
            int ra = wm * 64 + t * 16 + l4;
            aF[t] = *(const short8*)(sAc + ra * 64 + ((q ^ ((ra >> 1) & 3)) << 4));
            int rb = wn * 64 + t * 16 + l4;
            bF[t] = *(const short8*)(sBc + rb * 64 + ((q ^ ((rb >> 1) & 3)) << 4));
        }
#pragma unroll
        for (int tm = 0; tm < 4; ++tm)
#pragma unroll
            for (int tn = 0; tn < 4; ++tn)
                acc[tm][tn] = __builtin_amdgcn_mfma_f32_16x16x32_bf16(aF[tm], bF[tn], acc[tm][tn], 0, 0, 0);
        __syncthreads();
    }

    int sb = base[e];
#pragma unroll
    for (int tm = 0; tm < 4; ++tm) {
        int rbase = wm * 64 + tm * 16 + q * 4;
#pragma unroll
        for (int i = 0; i < 4; ++i) {
            int row = m0 + rbase + i;
            if (row < M) {
                size_t hrow = (size_t)(sb + row) * H_DIM;
#pragma unroll
                for (int tn = 0; tn < 4; ++tn) {
                    int col = n0 + wn * 64 + tn * 16 + l4;
                    float v = acc[tm][tn][i] + b1[e * H_DIM + col];
                    hbuf[hrow + col] = __float2bfloat16(gelu_exact(v));
                }
            }
        }
    }
}

// ---------------- GEMM2 (split-K=2): ybuf[kc][slot,:] = partial(h @ W2[e]) ----------------
__global__ __launch_bounds__(256) void gemm2_kernel(
    const __hip_bfloat16* __restrict__ hbuf, // [2T][H]
    const __hip_bfloat16* __restrict__ w2t,  // [E][D][H] (B^T layout)
    const int* __restrict__ cnt, const int* __restrict__ base,
    __hip_bfloat16* __restrict__ ybuf,       // [2][2T][D]
    int T) {
    int e = blockIdx.z >> 1;
    int kc = blockIdx.z & 1;
    int M = cnt[e];
    int m0 = blockIdx.y * 128;
    if (m0 >= M) return;
    int n0 = blockIdx.x * 128;
    int sb = base[e];
    const __hip_bfloat16* Bp = w2t + (size_t)e * D_DIM * H_DIM;

    __shared__ __align__(16) short sA[128 * 32];
    __shared__ __align__(16) short sB[128 * 32];
    char* sAc = (char*)sA; char* sBc = (char*)sB;

    int tid = threadIdx.x;
    int w = tid >> 6, lane = tid & 63;
    int wm = w >> 1, wn = w & 1;
    int q = lane >> 4, l4 = lane & 15;

    int kswz = ((lane & 3) ^ ((lane >> 3) & 3)) << 3;
    int r0 = w * 32 + (lane >> 2);
    int r1 = r0 + 16;
    const __hip_bfloat16* gA0 = hbuf + (size_t)(sb + min(m0 + r0, M - 1)) * H_DIM + kswz;
    const __hip_bfloat16* gA1 = hbuf + (size_t)(sb + min(m0 + r1, M - 1)) * H_DIM + kswz;
    const __hip_bfloat16* gB0 = Bp + (size_t)(n0 + r0) * H_DIM + kswz;
    const __hip_bfloat16* gB1 = Bp + (size_t)(n0 + r1) * H_DIM + kswz;
    char* lA0 = sAc + w * 2048; char* lA1 = lA0 + 1024;
    char* lB0 = sBc + w * 2048; char* lB1 = lB0 + 1024;

    f32x4 acc[4][4];
#pragma unroll
    for (int a = 0; a < 4; ++a)
#pragma unroll
        for (int b = 0; b < 4; ++b) acc[a][b] = (f32x4){0.f, 0.f, 0.f, 0.f};

    int k0 = kc * (H_DIM / 2), k1 = k0 + (H_DIM / 2);
    for (int kk = k0; kk < k1; kk += 32) {
        async_load16(gA0 + kk, lA0);
        async_load16(gA1 + kk, lA1);
        async_load16(gB0 + kk, lB0);
        async_load16(gB1 + kk, lB1);
        __syncthreads();
        short8 aF[4], bF[4];
#pragma unroll
        for (int t = 0; t < 4; ++t) {
            int ra = wm * 64 + t * 16 + l4;
            aF[t] = *(const short8*)(sAc + ra * 64 + ((q ^ ((ra >> 1) & 3)) << 4));
            int rb = wn * 64 + t * 16 + l4;
            bF[t] = *(const short8*)(sBc + rb * 64 + ((q ^ ((rb >> 1) & 3)) << 4));
        }
#pragma unroll
        for (int tm = 0; tm < 4; ++tm)
#pragma unroll
            for (int tn = 0; tn < 4; ++tn)
                acc[tm][tn] = __builtin_amdgcn_mfma_f32_16x16x32_bf16(aF[tm], bF[tn], acc[tm][tn], 0, 0, 0);
        __syncthreads();
    }

    size_t ybase = (size_t)kc * 2 * T;
#pragma unroll
    for (int tm = 0; tm < 4; ++tm) {
        int rbase = wm * 64 + tm * 16 + q * 4;
#pragma unroll
        for (int i = 0; i < 4; ++i) {
            int row = m0 + rbase + i;
            if (row < M) {
                size_t yrow = (ybase + sb + row) * D_DIM;
#pragma unroll
                for (int tn = 0; tn < 4; ++tn) {
                    int col = n0 + wn * 64 + tn * 16 + l4;
                    ybuf[yrow + col] = __float2bfloat16(acc[tm][tn][i]);
                }
            }
        }
    }
}

// ---------------- combine: out[t] = sum_j w_j * (y_j(part0)+y_j(part1) + b2[e_j]) ----------------
__global__ __launch_bounds__(256) void combine_kernel(
    const __hip_bfloat16* __restrict__ yb, const float* __restrict__ b2,
    const int* __restrict__ base, const int* __restrict__ eidx,
    const float* __restrict__ ewgt, float* __restrict__ out, int T) {
    int t = blockIdx.x, tid = threadIdx.x;
    int v0 = eidx[2 * t], v1 = eidx[2 * t + 1];
    float w0 = ewgt[2 * t], w1 = ewgt[2 * t + 1];
    int e0 = v0 >> 16, e1 = v1 >> 16;
    size_t g0 = (size_t)base[e0] + (v0 & 0xffff);
    size_t g1 = (size_t)base[e1] + (v1 & 0xffff);
    int c = tid * 4;
    size_t off2 = (size_t)2 * T * D_DIM;
    const short* ys = (const short*)yb;
    short4v a0 = *(const short4v*)(ys + g0 * D_DIM + c);
    short4v a1 = *(const short4v*)(ys + off2 + g0 * D_DIM + c);
    short4v c0 = *(const short4v*)(ys + g1 * D_DIM + c);
    short4v c1 = *(const short4v*)(ys + off2 + g1 * D_DIM + c);
    float4 bi0 = *(const float4*)(b2 + (size_t)e0 * D_DIM + c);
    float4 bi1 = *(const float4*)(b2 + (size_t)e1 * D_DIM + c);
    float4 o;
    o.x = w0 * (b2f(a0.x) + b2f(a1.x) + bi0.x) + w1 * (b2f(c0.x) + b2f(c1.x) + bi1.x);
    o.y = w0 * (b2f(a0.y) + b2f(a1.y) + bi0.y) + w1 * (b2f(c0.y) + b2f(c1.y) + bi1.y);
    o.z = w0 * (b2f(a0.z) + b2f(a1.z) + bi0.z) + w1 * (b2f(c0.z) + b2f(c1.z) + bi1.z);
    o.w = w0 * (b2f(a0.w) + b2f(a1.w) + bi0.w) + w1 * (b2f(c0.w) + b2f(c1.w) + bi1.w);
    *(float4*)(out + (size_t)t * D_DIM + c) = o;
}

extern "C" void kernel_launch(void* const* d_in, const int* in_sizes, int n_in,
                              void* d_out, int out_size, void* d_ws, size_t ws_size,
                              hipStream_t stream) {
    const float* x  = (const float*)d_in[0];
    const float* Wg = (const float*)d_in[1];
    const float* W1 = (const float*)d_in[2];
    const float* b1 = (const float*)d_in[3];
    const float* W2 = (const float*)d_in[4];
    const float* b2 = (const float*)d_in[5];
    int T = in_sizes[0] / D_DIM;  // 8192

    char* p = (char*)d_ws;
    int* cnt   = (int*)p;
    int* base  = (int*)(p + 256);
    int* tok   = (int*)(p + 512);
    int* eidx  = (int*)(p + 512 + 4ll * E_NUM * T);
    float* ewgt = (float*)(p + 512 + 4ll * E_NUM * T + 8ll * T);
    char* pb = p + 512 + 4ll * E_NUM * T + 16ll * T;
    __hip_bfloat16* xb  = (__hip_bfloat16*)pb;
    __hip_bfloat16* w1t = xb + (size_t)T * D_DIM;
    __hip_bfloat16* w2t = w1t + (size_t)E_NUM * H_DIM * D_DIM;
    __hip_bfloat16* hb  = w2t + (size_t)E_NUM * H_DIM * D_DIM;
    // ybuf [2][2T][D] bf16 (67 MB) aliases xb (16.7 MB) + w1t (67 MB): both are
    // dead by the time gemm2 runs; rewritten from d_in each call before reuse.
    __hip_bfloat16* yb  = xb;

    hipMemsetAsync(cnt, 0, 256, stream);

    router_kernel<<<dim3((T + 3) / 4), 256, 0, stream>>>(x, Wg, xb, cnt, tok, eidx, ewgt, T);
    prefix_kernel<<<1, 64, 0, stream>>>(cnt, base);
    transpose_conv_kernel<<<dim3(H_DIM / 32, D_DIM / 32, E_NUM), dim3(32, 8), 0, stream>>>(W1, w1t, D_DIM, H_DIM);
    transpose_conv_kernel<<<dim3(D_DIM / 32, H_DIM / 32, E_NUM), dim3(32, 8), 0, stream>>>(W2, w2t, H_DIM, D_DIM);
    gemm1_kernel<<<dim3(H_DIM / 128, T / 128, E_NUM), 256, 0, stream>>>(xb, w1t, b1, cnt, base, tok, hb, T);
    gemm2_kernel<<<dim3(D_DIM / 128, T / 128, E_NUM * 2), 256, 0, stream>>>(hb, w2t, cnt, base, yb, T);
    combine_kernel<<<T, 256, 0, stream>>>(yb, b2, base, eidx, ewgt, (float*)d_out, T);
}

// Round 3
// 906.471 us; speedup vs baseline: 1.1991x; 1.0860x over previous
//
#include <hip/hip_runtime.h>
#include <hip/hip_bf16.h>
#include <stdint.h>

#define D_DIM 1024
#define E_NUM 8
#define H_DIM 4096

typedef __attribute__((ext_vector_type(8))) short short8;
typedef __attribute__((ext_vector_type(4))) short short4v;
typedef __attribute__((ext_vector_type(4))) unsigned short ushort4v;
typedef __attribute__((ext_vector_type(4))) float f32x4;

#define GLOBAL_AS __attribute__((address_space(1)))
#define LDS_AS __attribute__((address_space(3)))

__device__ __forceinline__ void async_load16(const void* g, void* l) {
    __builtin_amdgcn_global_load_lds((GLOBAL_AS void*)g, (LDS_AS void*)l, 16, 0, 0);
}

// tanh-form gelu, branchless, ~13 VALU (vs erff ~20+). |err| <= ~3e-4, far
// under bf16 rounding of h.
__device__ __forceinline__ float gelu_fast(float x) {
    float x3 = x * x * x;
    float z = 0.7978845608028654f * x + 0.0356774081363001f * x3;
    float u = __expf(-2.0f * fabsf(z));
    float t = __fdividef(1.0f - u, 1.0f + u);
    t = copysignf(t, z);
    return 0.5f * x * (1.0f + t);
}

__device__ __forceinline__ float b2f(short s) {
    union { float f; unsigned u; } x; x.u = ((unsigned)(unsigned short)s) << 16; return x.f;
}

__device__ __forceinline__ unsigned short f2b(float f) {
    union { __hip_bfloat16 h; unsigned short s; } u;
    u.h = __float2bfloat16(f);
    return u.s;
}

// ---------------- router: logits (fp64), softmax, top-2, bucket append; fused x->bf16 ----------------
__global__ __launch_bounds__(256) void router_kernel(
    const float* __restrict__ x, const float* __restrict__ Wg,
    __hip_bfloat16* __restrict__ xb, int* __restrict__ cnt,
    int* __restrict__ tok, int* __restrict__ eidx, float* __restrict__ ewgt, int T) {
    int gwave = (int)((blockIdx.x * 256 + threadIdx.x) >> 6);
    int lane = threadIdx.x & 63;
    if (gwave >= T) return;
    const float* xr = x + (size_t)gwave * D_DIM;
    double acc[E_NUM];
#pragma unroll
    for (int e = 0; e < E_NUM; ++e) acc[e] = 0.0;
#pragma unroll
    for (int i = 0; i < D_DIM / 64; ++i) {
        int d = i * 64 + lane;
        float xv = xr[d];
        xb[(size_t)gwave * D_DIM + d] = __float2bfloat16(xv);
        const float4* wgp = (const float4*)(Wg + (size_t)d * E_NUM);
        float4 wa = wgp[0], wb = wgp[1];
        double xd = (double)xv;
        acc[0] += xd * (double)wa.x; acc[1] += xd * (double)wa.y;
        acc[2] += xd * (double)wa.z; acc[3] += xd * (double)wa.w;
        acc[4] += xd * (double)wb.x; acc[5] += xd * (double)wb.y;
        acc[6] += xd * (double)wb.z; acc[7] += xd * (double)wb.w;
    }
#pragma unroll
    for (int s = 32; s > 0; s >>= 1) {
#pragma unroll
        for (int e = 0; e < E_NUM; ++e) acc[e] += __shfl_xor(acc[e], s);
    }
    double mx = acc[0];
#pragma unroll
    for (int e = 1; e < E_NUM; ++e) mx = fmax(mx, acc[e]);
    double p[E_NUM]; double sum = 0.0;
#pragma unroll
    for (int e = 0; e < E_NUM; ++e) { p[e] = exp(acc[e] - mx); sum += p[e]; }
    int i0 = 0;
#pragma unroll
    for (int e = 1; e < E_NUM; ++e) if (p[e] > p[i0]) i0 = e;
    int i1 = (i0 == 0) ? 1 : 0;
#pragma unroll
    for (int e = 0; e < E_NUM; ++e) if (e != i0 && p[e] > p[i1]) i1 = e;
    float w0 = (float)(p[i0] / sum);
    float w1 = (float)(p[i1] / sum);
    if (lane == 0) {
        int s0 = atomicAdd(&cnt[i0], 1);
        tok[i0 * T + s0] = gwave;
        eidx[2 * gwave]     = (i0 << 16) | s0;
        ewgt[2 * gwave]     = w0;
        int s1 = atomicAdd(&cnt[i1], 1);
        tok[i1 * T + s1] = gwave;
        eidx[2 * gwave + 1] = (i1 << 16) | s1;
        ewgt[2 * gwave + 1] = w1;
    }
}

__global__ void prefix_kernel(const int* __restrict__ cnt, int* __restrict__ base) {
    if (threadIdx.x == 0) {
        int a = 0;
#pragma unroll
        for (int e = 0; e < E_NUM; ++e) { base[e] = a; a += cnt[e]; }
    }
}

// ---------------- W1 transpose + fp32->bf16: [E][D][H] f32 -> [E][H][D] bf16 ----------------
__global__ __launch_bounds__(256) void transpose_conv_kernel(
    const float* __restrict__ in, __hip_bfloat16* __restrict__ out, int R, int C) {
    __shared__ float tile[32][33];
    int e = blockIdx.z;
    int c0 = blockIdx.x * 32, r0 = blockIdx.y * 32;
    const float* ip = in + (size_t)e * R * C;
    __hip_bfloat16* op = out + (size_t)e * C * R;
    int tx = threadIdx.x, ty = threadIdx.y;
#pragma unroll
    for (int i = 0; i < 32; i += 8)
        tile[ty + i][tx] = ip[(size_t)(r0 + ty + i) * C + (c0 + tx)];
    __syncthreads();
#pragma unroll
    for (int i = 0; i < 32; i += 8)
        op[(size_t)(c0 + ty + i) * R + (r0 + tx)] = __float2bfloat16(tile[tx][ty + i]);
}

// ---------------- W2 transpose with permuted K(=H): w2t[e][d][h'] = W2[e][h0+pi(j)][d] ----------------
// pi(j) = (j&3)*16 + (j>>2) within each 64-block: matches gemm1's packed h store.
__global__ __launch_bounds__(256) void transpose_w2_kernel(
    const float* __restrict__ in, __hip_bfloat16* __restrict__ out) {
    __shared__ float tile[64][33];
    int e = blockIdx.z;
    int d0 = blockIdx.x * 32, h0 = blockIdx.y * 64;
    const float* ip = in + (size_t)e * H_DIM * D_DIM;
    unsigned short* op = (unsigned short*)(out + (size_t)e * D_DIM * H_DIM);
    int tx = threadIdx.x, ty = threadIdx.y;
#pragma unroll
    for (int i = 0; i < 64; i += 8) {
        int j = ty + i;
        int src = (j & 3) * 16 + (j >> 2);  // pi(j)
        tile[j][tx] = ip[(size_t)(h0 + src) * D_DIM + (d0 + tx)];
    }
    __syncthreads();
#pragma unroll
    for (int i = 0; i < 32; i += 8) {
        int d = ty + i;
        unsigned pk = (unsigned)f2b(tile[2 * tx][d]) | ((unsigned)f2b(tile[2 * tx + 1][d]) << 16);
        *(unsigned*)(op + (size_t)(d0 + d) * H_DIM + h0 + 2 * tx) = pk;
    }
}

// LDS K-chunk swizzle (round-2, conflict-free): row r chunk k stored at chunk r*4 + (k ^ ((r>>1)&3)).

// ---------------- GEMM1: h[slot, perm(col)] = gelu(x[tok] @ W1[e] + b1[e]) ----------------
__global__ __launch_bounds__(256) void gemm1_kernel(
    const __hip_bfloat16* __restrict__ xb,   // [T][D]
    const __hip_bfloat16* __restrict__ w1t,  // [E][H][D] (B^T layout)
    const float* __restrict__ b1,            // [E][H]
    const int* __restrict__ cnt, const int* __restrict__ base,
    const int* __restrict__ tok,
    __hip_bfloat16* __restrict__ hbuf,       // [2T][H] (N-permuted)
    int T) {
    int e = blockIdx.z;
    int M = cnt[e];
    int m0 = blockIdx.y * 128;
    if (m0 >= M) return;
    int n0 = blockIdx.x * 128;
    const __hip_bfloat16* Bp = w1t + (size_t)e * H_DIM * D_DIM;

    __shared__ __align__(16) short sA[128 * 32];
    __shared__ __align__(16) short sB[128 * 32];
    __shared__ float sBias[128];
    char* sAc = (char*)sA; char* sBc = (char*)sB;

    int tid = threadIdx.x;
    int w = tid >> 6, lane = tid & 63;
    int wm = w >> 1, wn = w & 1;
    int q = lane >> 4, l4 = lane & 15;

    if (tid < 128) sBias[tid] = b1[e * H_DIM + n0 + tid];

    int kswz = ((lane & 3) ^ ((lane >> 3) & 3)) << 3;  // swizzled element offset
    int r0 = w * 32 + (lane >> 2);
    int r1 = r0 + 16;
    int tA0 = tok[e * T + min(m0 + r0, M - 1)];
    int tA1 = tok[e * T + min(m0 + r1, M - 1)];
    const __hip_bfloat16* gA0 = xb + (size_t)tA0 * D_DIM + kswz;
    const __hip_bfloat16* gA1 = xb + (size_t)tA1 * D_DIM + kswz;
    const __hip_bfloat16* gB0 = Bp + (size_t)(n0 + r0) * D_DIM + kswz;
    const __hip_bfloat16* gB1 = Bp + (size_t)(n0 + r1) * D_DIM + kswz;
    char* lA0 = sAc + w * 2048; char* lA1 = lA0 + 1024;
    char* lB0 = sBc + w * 2048; char* lB1 = lB0 + 1024;

    f32x4 acc[4][4];
#pragma unroll
    for (int a = 0; a < 4; ++a)
#pragma unroll
        for (int b = 0; b < 4; ++b) acc[a][b] = (f32x4){0.f, 0.f, 0.f, 0.f};

    for (int kk = 0; kk < D_DIM; kk += 32) {
        async_load16(gA0 + kk, lA0);
        async_load16(gA1 + kk, lA1);
        async_load16(gB0 + kk, lB0);
        async_load16(gB1 + kk, lB1);
        __syncthreads();
        short8 aF[4], bF[4];
#pragma unroll
        for (int t = 0; t < 4; ++t) {
            int ra = wm * 64 + t * 16 + l4;
            aF[t] = *(const short8*)(sAc + ra * 64 + ((q ^ ((ra >> 1) & 3)) << 4));
            int rb = wn * 64 + t * 16 + l4;
            bF[t] = *(const short8*)(sBc + rb * 64 + ((q ^ ((rb >> 1) & 3)) << 4));
        }
#pragma unroll
        for (int tm = 0; tm < 4; ++tm)
#pragma unroll
            for (int tn = 0; tn < 4; ++tn)
                acc[tm][tn] = __builtin_amdgcn_mfma_f32_16x16x32_bf16(aF[tm], bF[tn], acc[tm][tn], 0, 0, 0);
        __syncthreads();
    }

    int sb = base[e];
    unsigned short* hs = (unsigned short*)hbuf;
#pragma unroll
    for (int tm = 0; tm < 4; ++tm) {
        int rbase = wm * 64 + tm * 16 + q * 4;
#pragma unroll
        for (int i = 0; i < 4; ++i) {
            int row = m0 + rbase + i;
            if (row < M) {
                size_t hrow = (size_t)(sb + row) * H_DIM;
                ushort4v pk;
#pragma unroll
                for (int tn = 0; tn < 4; ++tn) {
                    float v = acc[tm][tn][i] + sBias[wn * 64 + tn * 16 + l4];
                    pk[tn] = f2b(gelu_fast(v));
                }
                *(ushort4v*)(hs + hrow + n0 + wn * 64 + l4 * 4) = pk;
            }
        }
    }
}

// ---------------- GEMM2 (split-K=2): ybuf[kc][slot, perm(col)] = partial(h @ W2[e]) ----------------
__global__ __launch_bounds__(256) void gemm2_kernel(
    const __hip_bfloat16* __restrict__ hbuf, // [2T][H] (K-permuted, matches w2t)
    const __hip_bfloat16* __restrict__ w2t,  // [E][D][H] (B^T, K-permuted)
    const int* __restrict__ cnt, const int* __restrict__ base,
    __hip_bfloat16* __restrict__ ybuf,       // [2][2T][D] (N-permuted)
    int T) {
    int e = blockIdx.z >> 1;
    int kc = blockIdx.z & 1;
    int M = cnt[e];
    int m0 = blockIdx.y * 128;
    if (m0 >= M) return;
    int n0 = blockIdx.x * 128;
    int sb = base[e];
    const __hip_bfloat16* Bp = w2t + (size_t)e * D_DIM * H_DIM;

    __shared__ __align__(16) short sA[128 * 32];
    __shared__ __align__(16) short sB[128 * 32];
    char* sAc = (char*)sA; char* sBc = (char*)sB;

    int tid = threadIdx.x;
    int w = tid >> 6, lane = tid & 63;
    int wm = w >> 1, wn = w & 1;
    int q = lane >> 4, l4 = lane & 15;

    int kswz = ((lane & 3) ^ ((lane >> 3) & 3)) << 3;
    int r0 = w * 32 + (lane >> 2);
    int r1 = r0 + 16;
    const __hip_bfloat16* gA0 = hbuf + (size_t)(sb + min(m0 + r0, M - 1)) * H_DIM + kswz;
    const __hip_bfloat16* gA1 = hbuf + (size_t)(sb + min(m0 + r1, M - 1)) * H_DIM + kswz;
    const __hip_bfloat16* gB0 = Bp + (size_t)(n0 + r0) * H_DIM + kswz;
    const __hip_bfloat16* gB1 = Bp + (size_t)(n0 + r1) * H_DIM + kswz;
    char* lA0 = sAc + w * 2048; char* lA1 = lA0 + 1024;
    char* lB0 = sBc + w * 2048; char* lB1 = lB0 + 1024;

    f32x4 acc[4][4];
#pragma unroll
    for (int a = 0; a < 4; ++a)
#pragma unroll
        for (int b = 0; b < 4; ++b) acc[a][b] = (f32x4){0.f, 0.f, 0.f, 0.f};

    int k0 = kc * (H_DIM / 2), k1 = k0 + (H_DIM / 2);
    for (int kk = k0; kk < k1; kk += 32) {
        async_load16(gA0 + kk, lA0);
        async_load16(gA1 + kk, lA1);
        async_load16(gB0 + kk, lB0);
        async_load16(gB1 + kk, lB1);
        __syncthreads();
        short8 aF[4], bF[4];
#pragma unroll
        for (int t = 0; t < 4; ++t) {
            int ra = wm * 64 + t * 16 + l4;
            aF[t] = *(const short8*)(sAc + ra * 64 + ((q ^ ((ra >> 1) & 3)) << 4));
            int rb = wn * 64 + t * 16 + l4;
            bF[t] = *(const short8*)(sBc + rb * 64 + ((q ^ ((rb >> 1) & 3)) << 4));
        }
#pragma unroll
        for (int tm = 0; tm < 4; ++tm)
#pragma unroll
            for (int tn = 0; tn < 4; ++tn)
                acc[tm][tn] = __builtin_amdgcn_mfma_f32_16x16x32_bf16(aF[tm], bF[tn], acc[tm][tn], 0, 0, 0);
        __syncthreads();
    }

    size_t ybase = (size_t)kc * 2 * T;
    unsigned short* ys = (unsigned short*)ybuf;
#pragma unroll
    for (int tm = 0; tm < 4; ++tm) {
        int rbase = wm * 64 + tm * 16 + q * 4;
#pragma unroll
        for (int i = 0; i < 4; ++i) {
            int row = m0 + rbase + i;
            if (row < M) {
                size_t yrow = (ybase + sb + row) * D_DIM;
                ushort4v pk;
#pragma unroll
                for (int tn = 0; tn < 4; ++tn) pk[tn] = f2b(acc[tm][tn][i]);
                *(ushort4v*)(ys + yrow + n0 + wn * 64 + l4 * 4) = pk;
            }
        }
    }
}

// ---------------- combine: out[t, pi(c)] = sum_j w_j * (y_j(p0)+y_j(p1) + b2[e_j]) ----------------
__global__ __launch_bounds__(256) void combine_kernel(
    const __hip_bfloat16* __restrict__ yb, const float* __restrict__ b2,
    const int* __restrict__ base, const int* __restrict__ eidx,
    const float* __restrict__ ewgt, float* __restrict__ out, int T) {
    int t = blockIdx.x, tid = threadIdx.x;
    int v0 = eidx[2 * t], v1 = eidx[2 * t + 1];
    float w0 = ewgt[2 * t], w1 = ewgt[2 * t + 1];
    int e0 = v0 >> 16, e1 = v1 >> 16;
    size_t g0 = (size_t)base[e0] + (v0 & 0xffff);
    size_t g1 = (size_t)base[e1] + (v1 & 0xffff);
    int c = tid * 4;               // stored (permuted) col
    int blk = c >> 6;
    int tt = (c >> 2) & 15;
    size_t off2 = (size_t)2 * T * D_DIM;
    const short* ys = (const short*)yb;
    short4v a0 = *(const short4v*)(ys + g0 * D_DIM + c);
    short4v a1 = *(const short4v*)(ys + off2 + g0 * D_DIM + c);
    short4v c0 = *(const short4v*)(ys + g1 * D_DIM + c);
    short4v c1 = *(const short4v*)(ys + off2 + g1 * D_DIM + c);
    float s0[4] = { b2f(a0.x) + b2f(a1.x), b2f(a0.y) + b2f(a1.y),
                    b2f(a0.z) + b2f(a1.z), b2f(a0.w) + b2f(a1.w) };
    float s1[4] = { b2f(c0.x) + b2f(c1.x), b2f(c0.y) + b2f(c1.y),
                    b2f(c0.z) + b2f(c1.z), b2f(c0.w) + b2f(c1.w) };
    float* orow = out + (size_t)t * D_DIM;
#pragma unroll
    for (int s = 0; s < 4; ++s) {
        int oc = blk * 64 + s * 16 + tt;   // original col = pi(stored col)
        float o = w0 * (s0[s] + b2[(size_t)e0 * D_DIM + oc]) +
                  w1 * (s1[s] + b2[(size_t)e1 * D_DIM + oc]);
        orow[oc] = o;
    }
}

extern "C" void kernel_launch(void* const* d_in, const int* in_sizes, int n_in,
                              void* d_out, int out_size, void* d_ws, size_t ws_size,
                              hipStream_t stream) {
    const float* x  = (const float*)d_in[0];
    const float* Wg = (const float*)d_in[1];
    const float* W1 = (const float*)d_in[2];
    const float* b1 = (const float*)d_in[3];
    const float* W2 = (const float*)d_in[4];
    const float* b2 = (const float*)d_in[5];
    int T = in_sizes[0] / D_DIM;  // 8192

    char* p = (char*)d_ws;
    int* cnt   = (int*)p;
    int* base  = (int*)(p + 256);
    int* tok   = (int*)(p + 512);
    int* eidx  = (int*)(p + 512 + 4ll * E_NUM * T);
    float* ewgt = (float*)(p + 512 + 4ll * E_NUM * T + 8ll * T);
    char* pb = p + 512 + 4ll * E_NUM * T + 16ll * T;
    __hip_bfloat16* xb  = (__hip_bfloat16*)pb;
    __hip_bfloat16* w1t = xb + (size_t)T * D_DIM;
    __hip_bfloat16* w2t = w1t + (size_t)E_NUM * H_DIM * D_DIM;
    __hip_bfloat16* hb  = w2t + (size_t)E_NUM * H_DIM * D_DIM;
    // ybuf [2][2T][D] bf16 (67 MB) aliases xb (16.7 MB) + w1t (67 MB): both
    // dead by gemm2 time; rewritten from d_in each call before reuse.
    __hip_bfloat16* yb  = xb;

    hipMemsetAsync(cnt, 0, 256, stream);

    router_kernel<<<dim3((T + 3) / 4), 256, 0, stream>>>(x, Wg, xb, cnt, tok, eidx, ewgt, T);
    prefix_kernel<<<1, 64, 0, stream>>>(cnt, base);
    transpose_conv_kernel<<<dim3(H_DIM / 32, D_DIM / 32, E_NUM), dim3(32, 8), 0, stream>>>(W1, w1t, D_DIM, H_DIM);
    transpose_w2_kernel<<<dim3(D_DIM / 32, H_DIM / 64, E_NUM), dim3(32, 8), 0, stream>>>(W2, w2t);
    gemm1_kernel<<<dim3(H_DIM / 128, T / 128, E_NUM), 256, 0, stream>>>(xb, w1t, b1, cnt, base, tok, hb, T);
    gemm2_kernel<<<dim3(D_DIM / 128, T / 128, E_NUM * 2), 256, 0, stream>>>(hb, w2t, cnt, base, yb, T);
    combine_kernel<<<T, 256, 0, stream>>>(yb, b2, base, eidx, ewgt, (float*)d_out, T);
}

// Round 4
// 824.998 us; speedup vs baseline: 1.3176x; 1.0988x over previous
//
#include <hip/hip_runtime.h>
#include <hip/hip_bf16.h>
#include <stdint.h>

#define D_DIM 1024
#define E_NUM 8
#define H_DIM 4096

typedef __attribute__((ext_vector_type(8))) short short8;
typedef __attribute__((ext_vector_type(4))) short short4v;
typedef __attribute__((ext_vector_type(4))) unsigned short ushort4v;
typedef __attribute__((ext_vector_type(4))) float f32x4;

#define GLOBAL_AS __attribute__((address_space(1)))
#define LDS_AS __attribute__((address_space(3)))

__device__ __forceinline__ void async_load16(const void* g, void* l) {
    __builtin_amdgcn_global_load_lds((GLOBAL_AS void*)g, (LDS_AS void*)l, 16, 0, 0);
}

// tanh-form gelu, branchless. |err| <= ~3e-4.
__device__ __forceinline__ float gelu_fast(float x) {
    float x3 = x * x * x;
    float z = 0.7978845608028654f * x + 0.0356774081363001f * x3;
    float u = __expf(-2.0f * fabsf(z));
    float t = __fdividef(1.0f - u, 1.0f + u);
    t = copysignf(t, z);
    return 0.5f * x * (1.0f + t);
}

__device__ __forceinline__ float b2f(short s) {
    union { float f; unsigned u; } x; x.u = ((unsigned)(unsigned short)s) << 16; return x.f;
}

__device__ __forceinline__ unsigned short f2b(float f) {
    union { __hip_bfloat16 h; unsigned short s; } u;
    u.h = __float2bfloat16(f);
    return u.s;
}

// ---------------- router: logits (fp64), softmax, top-2; NO global atomics; fused x->bf16 ----------------
__global__ __launch_bounds__(256) void router_kernel(
    const float* __restrict__ x, const float* __restrict__ Wg,
    __hip_bfloat16* __restrict__ xb, int* __restrict__ epick,
    float* __restrict__ ewgt, int T) {
    int gwave = (int)((blockIdx.x * 256 + threadIdx.x) >> 6);
    int lane = threadIdx.x & 63;
    if (gwave >= T) return;
    const float* xr = x + (size_t)gwave * D_DIM;
    double acc[E_NUM];
#pragma unroll
    for (int e = 0; e < E_NUM; ++e) acc[e] = 0.0;
#pragma unroll
    for (int i = 0; i < D_DIM / 64; ++i) {
        int d = i * 64 + lane;
        float xv = xr[d];
        xb[(size_t)gwave * D_DIM + d] = __float2bfloat16(xv);
        const float4* wgp = (const float4*)(Wg + (size_t)d * E_NUM);
        float4 wa = wgp[0], wb = wgp[1];
        double xd = (double)xv;
        acc[0] += xd * (double)wa.x; acc[1] += xd * (double)wa.y;
        acc[2] += xd * (double)wa.z; acc[3] += xd * (double)wa.w;
        acc[4] += xd * (double)wb.x; acc[5] += xd * (double)wb.y;
        acc[6] += xd * (double)wb.z; acc[7] += xd * (double)wb.w;
    }
#pragma unroll
    for (int s = 32; s > 0; s >>= 1) {
#pragma unroll
        for (int e = 0; e < E_NUM; ++e) acc[e] += __shfl_xor(acc[e], s);
    }
    double mx = acc[0];
#pragma unroll
    for (int e = 1; e < E_NUM; ++e) mx = fmax(mx, acc[e]);
    double p[E_NUM]; double sum = 0.0;
#pragma unroll
    for (int e = 0; e < E_NUM; ++e) { p[e] = exp(acc[e] - mx); sum += p[e]; }
    int i0 = 0;
#pragma unroll
    for (int e = 1; e < E_NUM; ++e) if (p[e] > p[i0]) i0 = e;
    int i1 = (i0 == 0) ? 1 : 0;
#pragma unroll
    for (int e = 0; e < E_NUM; ++e) if (e != i0 && p[e] > p[i1]) i1 = e;
    if (lane == 0) {
        epick[gwave] = i0 | (i1 << 8);
        ewgt[2 * gwave]     = (float)(p[i0] / sum);
        ewgt[2 * gwave + 1] = (float)(p[i1] / sum);
    }
}

// ---------------- bucket: block-aggregated scatter; 8 global atomics per block ----------------
__global__ __launch_bounds__(256) void bucket_kernel(
    const int* __restrict__ epick, int* __restrict__ cnt,
    int* __restrict__ tok, int* __restrict__ eidx, int T) {
    __shared__ int lcnt[E_NUM];
    __shared__ int gbase[E_NUM];
    int b = blockIdx.x, tid = threadIdx.x;
    if (tid < E_NUM) lcnt[tid] = 0;
    __syncthreads();
    int t = b * 128 + (tid >> 1);
    int j = tid & 1;
    int e = (epick[t] >> (j * 8)) & 0xff;
    int li = atomicAdd(&lcnt[e], 1);
    __syncthreads();
    if (tid < E_NUM) gbase[tid] = atomicAdd(&cnt[tid], lcnt[tid]);
    __syncthreads();
    int slot = gbase[e] + li;
    tok[e * T + slot] = t;
    eidx[2 * t + j] = (e << 16) | slot;
}

__global__ void prefix_kernel(const int* __restrict__ cnt, int* __restrict__ base) {
    if (threadIdx.x == 0) {
        int a = 0;
#pragma unroll
        for (int e = 0; e < E_NUM; ++e) { base[e] = a; a += cnt[e]; }
    }
}

// ---------------- unified W1/W2 transpose, 64x64 tiles, packed stores ----------------
// W1: [E][D][H] f32 -> w1t [E][H][D] bf16 (no perm).
// W2: [E][H][D] f32 -> w2t [E][D][H] bf16 with K(=H) perm pi(j)=(j&3)*16+(j>>2) per 64-block.
__global__ __launch_bounds__(256) void transpose_both_kernel(
    const float* __restrict__ W1, const float* __restrict__ W2,
    __hip_bfloat16* __restrict__ w1t, __hip_bfloat16* __restrict__ w2t) {
    __shared__ float tile[64][65];
    int e = blockIdx.z;
    int id = blockIdx.x;
    const float* src; unsigned short* dst; int R, C, r0, c0, perm;
    if (id < 1024) {  // W1: R=D rows, C=H cols; tiles 16 x 64
        R = D_DIM; C = H_DIM;
        r0 = (id >> 6) * 64; c0 = (id & 63) * 64;
        src = W1 + (size_t)e * D_DIM * H_DIM;
        dst = (unsigned short*)(w1t + (size_t)e * H_DIM * D_DIM);
        perm = 0;
    } else {          // W2: R=H rows, C=D cols; tiles 64 x 16
        id -= 1024;
        R = H_DIM; C = D_DIM;
        r0 = (id >> 4) * 64; c0 = (id & 15) * 64;
        src = W2 + (size_t)e * H_DIM * D_DIM;
        dst = (unsigned short*)(w2t + (size_t)e * D_DIM * H_DIM);
        perm = 1;
    }
    int tx = threadIdx.x, ty = threadIdx.y;  // 32 x 8
#pragma unroll
    for (int i = 0; i < 8; ++i) {
        int j = ty + i * 8;
        int sr = perm ? ((j & 3) * 16 + (j >> 2)) : j;
        float2 v = *(const float2*)(src + (size_t)(r0 + sr) * C + c0 + 2 * tx);
        tile[j][2 * tx] = v.x; tile[j][2 * tx + 1] = v.y;
    }
    __syncthreads();
#pragma unroll
    for (int i = 0; i < 8; ++i) {
        int cc = ty + i * 8;
        unsigned pk = (unsigned)f2b(tile[2 * tx][cc]) | ((unsigned)f2b(tile[2 * tx + 1][cc]) << 16);
        *(unsigned*)(dst + (size_t)(c0 + cc) * R + r0 + 2 * tx) = pk;
    }
}

// LDS swizzle (BK=64, 128 B rows = 8 chunks): row r chunk c stored at c ^ (r&7).
// Writer (async, dest = base + lane*16): lane covers row (lane>>3), sources global
// chunk (lane&7)^(lane>>3) -> still a full 128 B per 8 lanes, coalesced.
// Reader: chunk cg of row ra at byte ra*128 + ((cg ^ (ra&7))<<4). Per 16-lane
// phase: all 8 bank-groups hit exactly twice = free 2-way.

// ---------------- GEMM1: h[slot, perm(col)] = gelu(x[tok] @ W1[e] + b1[e]), BK=64 ----------------
__global__ __launch_bounds__(256) void gemm1_kernel(
    const __hip_bfloat16* __restrict__ xb,   // [T][D]
    const __hip_bfloat16* __restrict__ w1t,  // [E][H][D] (B^T)
    const float* __restrict__ b1,            // [E][H]
    const int* __restrict__ cnt, const int* __restrict__ base,
    const int* __restrict__ tok,
    __hip_bfloat16* __restrict__ hbuf,       // [2T][H] (N-permuted)
    int T) {
    int e = blockIdx.z;
    int M = cnt[e];
    int m0 = blockIdx.y * 128;
    if (m0 >= M) return;
    int n0 = blockIdx.x * 128;
    const __hip_bfloat16* Bp = w1t + (size_t)e * H_DIM * D_DIM;

    __shared__ __align__(16) short sA[128 * 64];
    __shared__ __align__(16) short sB[128 * 64];
    __shared__ float sBias[128];
    char* sAc = (char*)sA; char* sBc = (char*)sB;

    int tid = threadIdx.x;
    int w = tid >> 6, lane = tid & 63;
    int wm = w >> 1, wn = w & 1;
    int q = lane >> 4, l4 = lane & 15;

    if (tid < 128) sBias[tid] = b1[e * H_DIM + n0 + tid];

    int rl = lane >> 3;                // 0..7
    int g = (lane & 7) ^ rl;           // permuted global chunk
    const __hip_bfloat16* gA[4]; const __hip_bfloat16* gB[4];
#pragma unroll
    for (int i = 0; i < 4; ++i) {
        int r = w * 32 + i * 8 + rl;
        int tA = tok[e * T + min(m0 + r, M - 1)];
        gA[i] = xb + (size_t)tA * D_DIM + g * 8;
        gB[i] = Bp + (size_t)(n0 + r) * D_DIM + g * 8;
    }
    char* lA = sAc + w * 4096 + lane * 16;
    char* lB = sBc + w * 4096 + lane * 16;

    f32x4 acc[4][4];
#pragma unroll
    for (int a = 0; a < 4; ++a)
#pragma unroll
        for (int b = 0; b < 4; ++b) acc[a][b] = (f32x4){0.f, 0.f, 0.f, 0.f};

    for (int kk = 0; kk < D_DIM; kk += 64) {
#pragma unroll
        for (int i = 0; i < 4; ++i) async_load16(gA[i] + kk, lA + i * 1024);
#pragma unroll
        for (int i = 0; i < 4; ++i) async_load16(gB[i] + kk, lB + i * 1024);
        __syncthreads();
#pragma unroll
        for (int s = 0; s < 2; ++s) {
            short8 aF[4], bF[4];
            int cg = s * 4 + q;
#pragma unroll
            for (int t = 0; t < 4; ++t) {
                int ra = wm * 64 + t * 16 + l4;
                aF[t] = *(const short8*)(sAc + ra * 128 + ((cg ^ (ra & 7)) << 4));
                int rb = wn * 64 + t * 16 + l4;
                bF[t] = *(const short8*)(sBc + rb * 128 + ((cg ^ (rb & 7)) << 4));
            }
#pragma unroll
            for (int tm = 0; tm < 4; ++tm)
#pragma unroll
                for (int tn = 0; tn < 4; ++tn)
                    acc[tm][tn] = __builtin_amdgcn_mfma_f32_16x16x32_bf16(aF[tm], bF[tn], acc[tm][tn], 0, 0, 0);
        }
        __syncthreads();
    }

    int sb = base[e];
    unsigned short* hs = (unsigned short*)hbuf;
#pragma unroll
    for (int tm = 0; tm < 4; ++tm) {
        int rbase = wm * 64 + tm * 16 + q * 4;
#pragma unroll
        for (int i = 0; i < 4; ++i) {
            int row = m0 + rbase + i;
            if (row < M) {
                size_t hrow = (size_t)(sb + row) * H_DIM;
                ushort4v pk;
#pragma unroll
                for (int tn = 0; tn < 4; ++tn) {
                    float v = acc[tm][tn][i] + sBias[wn * 64 + tn * 16 + l4];
                    pk[tn] = f2b(gelu_fast(v));
                }
                *(ushort4v*)(hs + hrow + n0 + wn * 64 + l4 * 4) = pk;
            }
        }
    }
}

// ---------------- GEMM2 (split-K=2, BK=64): ybuf[kc][slot, perm(col)] = partial(h @ W2[e]) ----------------
__global__ __launch_bounds__(256) void gemm2_kernel(
    const __hip_bfloat16* __restrict__ hbuf, // [2T][H] (K-permuted, matches w2t)
    const __hip_bfloat16* __restrict__ w2t,  // [E][D][H] (B^T, K-permuted)
    const int* __restrict__ cnt, const int* __restrict__ base,
    __hip_bfloat16* __restrict__ ybuf,       // [2][2T][D] (N-permuted)
    int T) {
    int e = blockIdx.z >> 1;
    int kc = blockIdx.z & 1;
    int M = cnt[e];
    int m0 = blockIdx.y * 128;
    if (m0 >= M) return;
    int n0 = blockIdx.x * 128;
    int sb = base[e];
    const __hip_bfloat16* Bp = w2t + (size_t)e * D_DIM * H_DIM;

    __shared__ __align__(16) short sA[128 * 64];
    __shared__ __align__(16) short sB[128 * 64];
    char* sAc = (char*)sA; char* sBc = (char*)sB;

    int tid = threadIdx.x;
    int w = tid >> 6, lane = tid & 63;
    int wm = w >> 1, wn = w & 1;
    int q = lane >> 4, l4 = lane & 15;

    int rl = lane >> 3;
    int g = (lane & 7) ^ rl;
    const __hip_bfloat16* gA[4]; const __hip_bfloat16* gB[4];
#pragma unroll
    for (int i = 0; i < 4; ++i) {
        int r = w * 32 + i * 8 + rl;
        gA[i] = hbuf + (size_t)(sb + min(m0 + r, M - 1)) * H_DIM + g * 8;
        gB[i] = Bp + (size_t)(n0 + r) * H_DIM + g * 8;
    }
    char* lA = sAc + w * 4096 + lane * 16;
    char* lB = sBc + w * 4096 + lane * 16;

    f32x4 acc[4][4];
#pragma unroll
    for (int a = 0; a < 4; ++a)
#pragma unroll
        for (int b = 0; b < 4; ++b) acc[a][b] = (f32x4){0.f, 0.f, 0.f, 0.f};

    int k0 = kc * (H_DIM / 2), k1 = k0 + (H_DIM / 2);
    for (int kk = k0; kk < k1; kk += 64) {
#pragma unroll
        for (int i = 0; i < 4; ++i) async_load16(gA[i] + kk, lA + i * 1024);
#pragma unroll
        for (int i = 0; i < 4; ++i) async_load16(gB[i] + kk, lB + i * 1024);
        __syncthreads();
#pragma unroll
        for (int s = 0; s < 2; ++s) {
            short8 aF[4], bF[4];
            int cg = s * 4 + q;
#pragma unroll
            for (int t = 0; t < 4; ++t) {
                int ra = wm * 64 + t * 16 + l4;
                aF[t] = *(const short8*)(sAc + ra * 128 + ((cg ^ (ra & 7)) << 4));
                int rb = wn * 64 + t * 16 + l4;
                bF[t] = *(const short8*)(sBc + rb * 128 + ((cg ^ (rb & 7)) << 4));
            }
#pragma unroll
            for (int tm = 0; tm < 4; ++tm)
#pragma unroll
                for (int tn = 0; tn < 4; ++tn)
                    acc[tm][tn] = __builtin_amdgcn_mfma_f32_16x16x32_bf16(aF[tm], bF[tn], acc[tm][tn], 0, 0, 0);
        }
        __syncthreads();
    }

    size_t ybase = (size_t)kc * 2 * T;
    unsigned short* ys = (unsigned short*)ybuf;
#pragma unroll
    for (int tm = 0; tm < 4; ++tm) {
        int rbase = wm * 64 + tm * 16 + q * 4;
#pragma unroll
        for (int i = 0; i < 4; ++i) {
            int row = m0 + rbase + i;
            if (row < M) {
                size_t yrow = (ybase + sb + row) * D_DIM;
                ushort4v pk;
#pragma unroll
                for (int tn = 0; tn < 4; ++tn) pk[tn] = f2b(acc[tm][tn][i]);
                *(ushort4v*)(ys + yrow + n0 + wn * 64 + l4 * 4) = pk;
            }
        }
    }
}

// ---------------- combine: out[t, pi(c)] = sum_j w_j * (y_j(p0)+y_j(p1) + b2[e_j]) ----------------
__global__ __launch_bounds__(256) void combine_kernel(
    const __hip_bfloat16* __restrict__ yb, const float* __restrict__ b2,
    const int* __restrict__ base, const int* __restrict__ eidx,
    const float* __restrict__ ewgt, float* __restrict__ out, int T) {
    int t = blockIdx.x, tid = threadIdx.x;
    int v0 = eidx[2 * t], v1 = eidx[2 * t + 1];
    float w0 = ewgt[2 * t], w1 = ewgt[2 * t + 1];
    int e0 = v0 >> 16, e1 = v1 >> 16;
    size_t g0 = (size_t)base[e0] + (v0 & 0xffff);
    size_t g1 = (size_t)base[e1] + (v1 & 0xffff);
    int c = tid * 4;               // stored (permuted) col
    int blk = c >> 6;
    int tt = (c >> 2) & 15;
    size_t off2 = (size_t)2 * T * D_DIM;
    const short* ys = (const short*)yb;
    short4v a0 = *(const short4v*)(ys + g0 * D_DIM + c);
    short4v a1 = *(const short4v*)(ys + off2 + g0 * D_DIM + c);
    short4v c0 = *(const short4v*)(ys + g1 * D_DIM + c);
    short4v c1 = *(const short4v*)(ys + off2 + g1 * D_DIM + c);
    float s0[4] = { b2f(a0.x) + b2f(a1.x), b2f(a0.y) + b2f(a1.y),
                    b2f(a0.z) + b2f(a1.z), b2f(a0.w) + b2f(a1.w) };
    float s1[4] = { b2f(c0.x) + b2f(c1.x), b2f(c0.y) + b2f(c1.y),
                    b2f(c0.z) + b2f(c1.z), b2f(c0.w) + b2f(c1.w) };
    float* orow = out + (size_t)t * D_DIM;
#pragma unroll
    for (int s = 0; s < 4; ++s) {
        int oc = blk * 64 + s * 16 + tt;   // original col
        float o = w0 * (s0[s] + b2[(size_t)e0 * D_DIM + oc]) +
                  w1 * (s1[s] + b2[(size_t)e1 * D_DIM + oc]);
        orow[oc] = o;
    }
}

extern "C" void kernel_launch(void* const* d_in, const int* in_sizes, int n_in,
                              void* d_out, int out_size, void* d_ws, size_t ws_size,
                              hipStream_t stream) {
    const float* x  = (const float*)d_in[0];
    const float* Wg = (const float*)d_in[1];
    const float* W1 = (const float*)d_in[2];
    const float* b1 = (const float*)d_in[3];
    const float* W2 = (const float*)d_in[4];
    const float* b2 = (const float*)d_in[5];
    int T = in_sizes[0] / D_DIM;  // 8192

    char* p = (char*)d_ws;
    int* cnt   = (int*)p;
    int* base  = (int*)(p + 256);
    int* tok   = (int*)(p + 512);
    int* eidx  = (int*)(p + 512 + 4ll * E_NUM * T);
    float* ewgt = (float*)(p + 512 + 4ll * E_NUM * T + 8ll * T);
    int* epick = (int*)(p + 512 + 4ll * E_NUM * T + 16ll * T);
    char* pb = p + 512 + 4ll * E_NUM * T + 20ll * T;
    __hip_bfloat16* xb  = (__hip_bfloat16*)pb;
    __hip_bfloat16* w1t = xb + (size_t)T * D_DIM;
    __hip_bfloat16* w2t = w1t + (size_t)E_NUM * H_DIM * D_DIM;
    __hip_bfloat16* hb  = w2t + (size_t)E_NUM * H_DIM * D_DIM;
    // ybuf [2][2T][D] bf16 (67 MB) aliases xb+w1t (dead by gemm2 time).
    __hip_bfloat16* yb  = xb;

    hipMemsetAsync(cnt, 0, 256, stream);

    router_kernel<<<dim3((T + 3) / 4), 256, 0, stream>>>(x, Wg, xb, epick, ewgt, T);
    bucket_kernel<<<dim3(T / 128), 256, 0, stream>>>(epick, cnt, tok, eidx, T);
    prefix_kernel<<<1, 64, 0, stream>>>(cnt, base);
    transpose_both_kernel<<<dim3(2048, 1, E_NUM), dim3(32, 8), 0, stream>>>(W1, W2, w1t, w2t);
    gemm1_kernel<<<dim3(H_DIM / 128, T / 128, E_NUM), 256, 0, stream>>>(xb, w1t, b1, cnt, base, tok, hb, T);
    gemm2_kernel<<<dim3(D_DIM / 128, T / 128, E_NUM * 2), 256, 0, stream>>>(hb, w2t, cnt, base, yb, T);
    combine_kernel<<<T, 256, 0, stream>>>(yb, b2, base, eidx, ewgt, (float*)d_out, T);
}

// Round 5
// 738.868 us; speedup vs baseline: 1.4712x; 1.1166x over previous
//
#include <hip/hip_runtime.h>
#include <hip/hip_bf16.h>
#include <stdint.h>

#define D_DIM 1024
#define E_NUM 8
#define H_DIM 4096

typedef __attribute__((ext_vector_type(8))) short short8;
typedef __attribute__((ext_vector_type(4))) short short4v;
typedef __attribute__((ext_vector_type(4))) unsigned short ushort4v;
typedef __attribute__((ext_vector_type(4))) float f32x4;

#define GLOBAL_AS __attribute__((address_space(1)))
#define LDS_AS __attribute__((address_space(3)))

__device__ __forceinline__ void async_load16(const void* g, void* l) {
    __builtin_amdgcn_global_load_lds((GLOBAL_AS void*)g, (LDS_AS void*)l, 16, 0, 0);
}

// tanh-form gelu, branchless. |err| <= ~3e-4.
__device__ __forceinline__ float gelu_fast(float x) {
    float x3 = x * x * x;
    float z = 0.7978845608028654f * x + 0.0356774081363001f * x3;
    float u = __expf(-2.0f * fabsf(z));
    float t = __fdividef(1.0f - u, 1.0f + u);
    t = copysignf(t, z);
    return 0.5f * x * (1.0f + t);
}

__device__ __forceinline__ float b2f(short s) {
    union { float f; unsigned u; } x; x.u = ((unsigned)(unsigned short)s) << 16; return x.f;
}

__device__ __forceinline__ unsigned short f2b(float f) {
    union { __hip_bfloat16 h; unsigned short s; } u;
    u.h = __float2bfloat16(f);
    return u.s;
}

// ---------------- router: logits (fp64), softmax, top-2; NO global atomics; fused x->bf16 ----------------
__global__ __launch_bounds__(256) void router_kernel(
    const float* __restrict__ x, const float* __restrict__ Wg,
    __hip_bfloat16* __restrict__ xb, int* __restrict__ epick,
    float* __restrict__ ewgt, int T) {
    int gwave = (int)((blockIdx.x * 256 + threadIdx.x) >> 6);
    int lane = threadIdx.x & 63;
    if (gwave >= T) return;
    const float* xr = x + (size_t)gwave * D_DIM;
    double acc[E_NUM];
#pragma unroll
    for (int e = 0; e < E_NUM; ++e) acc[e] = 0.0;
#pragma unroll
    for (int i = 0; i < D_DIM / 64; ++i) {
        int d = i * 64 + lane;
        float xv = xr[d];
        xb[(size_t)gwave * D_DIM + d] = __float2bfloat16(xv);
        const float4* wgp = (const float4*)(Wg + (size_t)d * E_NUM);
        float4 wa = wgp[0], wb = wgp[1];
        double xd = (double)xv;
        acc[0] += xd * (double)wa.x; acc[1] += xd * (double)wa.y;
        acc[2] += xd * (double)wa.z; acc[3] += xd * (double)wa.w;
        acc[4] += xd * (double)wb.x; acc[5] += xd * (double)wb.y;
        acc[6] += xd * (double)wb.z; acc[7] += xd * (double)wb.w;
    }
#pragma unroll
    for (int s = 32; s > 0; s >>= 1) {
#pragma unroll
        for (int e = 0; e < E_NUM; ++e) acc[e] += __shfl_xor(acc[e], s);
    }
    double mx = acc[0];
#pragma unroll
    for (int e = 1; e < E_NUM; ++e) mx = fmax(mx, acc[e]);
    double p[E_NUM]; double sum = 0.0;
#pragma unroll
    for (int e = 0; e < E_NUM; ++e) { p[e] = exp(acc[e] - mx); sum += p[e]; }
    int i0 = 0;
#pragma unroll
    for (int e = 1; e < E_NUM; ++e) if (p[e] > p[i0]) i0 = e;
    int i1 = (i0 == 0) ? 1 : 0;
#pragma unroll
    for (int e = 0; e < E_NUM; ++e) if (e != i0 && p[e] > p[i1]) i1 = e;
    if (lane == 0) {
        epick[gwave] = i0 | (i1 << 8);
        ewgt[2 * gwave]     = (float)(p[i0] / sum);
        ewgt[2 * gwave + 1] = (float)(p[i1] / sum);
    }
}

// ---------------- bucket: block-aggregated scatter; 8 global atomics per block ----------------
__global__ __launch_bounds__(256) void bucket_kernel(
    const int* __restrict__ epick, int* __restrict__ cnt,
    int* __restrict__ tok, int* __restrict__ eidx, int T) {
    __shared__ int lcnt[E_NUM];
    __shared__ int gbase[E_NUM];
    int b = blockIdx.x, tid = threadIdx.x;
    if (tid < E_NUM) lcnt[tid] = 0;
    __syncthreads();
    int t = b * 128 + (tid >> 1);
    int j = tid & 1;
    int e = (epick[t] >> (j * 8)) & 0xff;
    int li = atomicAdd(&lcnt[e], 1);
    __syncthreads();
    if (tid < E_NUM) gbase[tid] = atomicAdd(&cnt[tid], lcnt[tid]);
    __syncthreads();
    int slot = gbase[e] + li;
    tok[e * T + slot] = t;
    eidx[2 * t + j] = (e << 16) | slot;
}

__global__ void prefix_kernel(const int* __restrict__ cnt, int* __restrict__ base) {
    if (threadIdx.x == 0) {
        int a = 0;
#pragma unroll
        for (int e = 0; e < E_NUM; ++e) { base[e] = a; a += cnt[e]; }
    }
}

// ---------------- unified W1/W2 transpose, 64x64 tiles, packed stores ----------------
// W1: [E][D][H] f32 -> w1t [E][H][D] bf16 (no perm).
// W2: [E][H][D] f32 -> w2t [E][D][H] bf16 with K(=H) perm pi(j)=(j&3)*16+(j>>2) per 64-block.
__global__ __launch_bounds__(256) void transpose_both_kernel(
    const float* __restrict__ W1, const float* __restrict__ W2,
    __hip_bfloat16* __restrict__ w1t, __hip_bfloat16* __restrict__ w2t) {
    __shared__ float tile[64][65];
    int e = blockIdx.z;
    int id = blockIdx.x;
    const float* src; unsigned short* dst; int R, C, r0, c0, perm;
    if (id < 1024) {  // W1: R=D rows, C=H cols
        R = D_DIM; C = H_DIM;
        r0 = (id >> 6) * 64; c0 = (id & 63) * 64;
        src = W1 + (size_t)e * D_DIM * H_DIM;
        dst = (unsigned short*)(w1t + (size_t)e * H_DIM * D_DIM);
        perm = 0;
    } else {          // W2: R=H rows, C=D cols
        id -= 1024;
        R = H_DIM; C = D_DIM;
        r0 = (id >> 4) * 64; c0 = (id & 15) * 64;
        src = W2 + (size_t)e * H_DIM * D_DIM;
        dst = (unsigned short*)(w2t + (size_t)e * D_DIM * H_DIM);
        perm = 1;
    }
    int tx = threadIdx.x, ty = threadIdx.y;  // 32 x 8
#pragma unroll
    for (int i = 0; i < 8; ++i) {
        int j = ty + i * 8;
        int sr = perm ? ((j & 3) * 16 + (j >> 2)) : j;
        float2 v = *(const float2*)(src + (size_t)(r0 + sr) * C + c0 + 2 * tx);
        tile[j][2 * tx] = v.x; tile[j][2 * tx + 1] = v.y;
    }
    __syncthreads();
#pragma unroll
    for (int i = 0; i < 8; ++i) {
        int cc = ty + i * 8;
        unsigned pk = (unsigned)f2b(tile[2 * tx][cc]) | ((unsigned)f2b(tile[2 * tx + 1][cc]) << 16);
        *(unsigned*)(dst + (size_t)(c0 + cc) * R + r0 + 2 * tx) = pk;
    }
}

// LDS K-chunk swizzle (BK=32, 64 B rows = 4 chunks): row r chunk k stored at
// chunk r*4 + (k ^ ((r>>1)&3)). Writer (async, dest = base+lane*16): lane
// sources global chunk (lane&3)^((lane>>3)&3) of row (lane>>2). Reader: chunk
// q of row ra at byte ra*64 + ((q ^ ((ra>>1)&3))<<4). Conflict-free (measured
// round 2: SQ_LDS_BANK_CONFLICT 1.73e7 -> 0).
// NOTE round-4 post-mortem: BK=64 regressed (VGPR 60->92, LDS 17->33KB,
// occupancy 41->21%, MfmaUtil 30->23) — m132's lesson. Keep BK=32.

// ---------------- GEMM1: h[slot, perm(col)] = gelu(x[tok] @ W1[e] + b1[e]), BK=32 ----------------
__global__ __launch_bounds__(256) void gemm1_kernel(
    const __hip_bfloat16* __restrict__ xb,   // [T][D]
    const __hip_bfloat16* __restrict__ w1t,  // [E][H][D] (B^T)
    const float* __restrict__ b1,            // [E][H]
    const int* __restrict__ cnt, const int* __restrict__ base,
    const int* __restrict__ tok,
    __hip_bfloat16* __restrict__ hbuf,       // [2T][H] (N-permuted)
    int T) {
    int e = blockIdx.z;
    int M = cnt[e];
    int m0 = blockIdx.y * 128;
    if (m0 >= M) return;
    int n0 = blockIdx.x * 128;
    const __hip_bfloat16* Bp = w1t + (size_t)e * H_DIM * D_DIM;

    __shared__ __align__(16) short sA[128 * 32];
    __shared__ __align__(16) short sB[128 * 32];
    __shared__ float sBias[128];
    char* sAc = (char*)sA; char* sBc = (char*)sB;

    int tid = threadIdx.x;
    int w = tid >> 6, lane = tid & 63;
    int wm = w >> 1, wn = w & 1;
    int q = lane >> 4, l4 = lane & 15;

    if (tid < 128) sBias[tid] = b1[e * H_DIM + n0 + tid];

    int kswz = ((lane & 3) ^ ((lane >> 3) & 3)) << 3;  // swizzled element offset
    int r0 = w * 32 + (lane >> 2);
    int r1 = r0 + 16;
    int tA0 = tok[e * T + min(m0 + r0, M - 1)];
    int tA1 = tok[e * T + min(m0 + r1, M - 1)];
    const __hip_bfloat16* gA0 = xb + (size_t)tA0 * D_DIM + kswz;
    const __hip_bfloat16* gA1 = xb + (size_t)tA1 * D_DIM + kswz;
    const __hip_bfloat16* gB0 = Bp + (size_t)(n0 + r0) * D_DIM + kswz;
    const __hip_bfloat16* gB1 = Bp + (size_t)(n0 + r1) * D_DIM + kswz;
    char* lA0 = sAc + w * 2048 + (lane & 3) * 16 + (lane >> 2) * 64;
    char* lB0 = sBc + w * 2048 + (lane & 3) * 16 + (lane >> 2) * 64;
    // NOTE: async dest must be base + lane*16 in wave-lane order; w*2048 +
    // lane*16 equals the expression above only if layout matches — keep the
    // original proven form:
    lA0 = sAc + w * 2048 + lane * 16 - lane * 16 + lane * 16;  // = sAc + w*2048 + lane*16
    lA0 = sAc + w * 2048 + lane * 16;
    lB0 = sBc + w * 2048 + lane * 16;
    char* lA1 = sAc + w * 2048 + 1024 + (lane * 16) - (lane * 16);
    lA1 = sAc + w * 2048 + 1024;  // wave's second segment base
    char* lB1 = sBc + w * 2048 + 1024;
    // per-lane second-segment dest:
    lA1 += 0; lB1 += 0;

    f32x4 acc[4][4];
#pragma unroll
    for (int a = 0; a < 4; ++a)
#pragma unroll
        for (int b = 0; b < 4; ++b) acc[a][b] = (f32x4){0.f, 0.f, 0.f, 0.f};

    for (int kk = 0; kk < D_DIM; kk += 32) {
        async_load16(gA0 + kk, lA0);
        async_load16(gA1 + kk, lA1);
        async_load16(gB0 + kk, lB0);
        async_load16(gB1 + kk, lB1);
        __syncthreads();
        short8 aF[4], bF[4];
#pragma unroll
        for (int t = 0; t < 4; ++t) {
            int ra = wm * 64 + t * 16 + l4;
            aF[t] = *(const short8*)(sAc + ra * 64 + ((q ^ ((ra >> 1) & 3)) << 4));
            int rb = wn * 64 + t * 16 + l4;
            bF[t] = *(const short8*)(sBc + rb * 64 + ((q ^ ((rb >> 1) & 3)) << 4));
        }
#pragma unroll
        for (int tm = 0; tm < 4; ++tm)
#pragma unroll
            for (int tn = 0; tn < 4; ++tn)
                acc[tm][tn] = __builtin_amdgcn_mfma_f32_16x16x32_bf16(aF[tm], bF[tn], acc[tm][tn], 0, 0, 0);
        __syncthreads();
    }

    int sb = base[e];
    unsigned short* hs = (unsigned short*)hbuf;
#pragma unroll
    for (int tm = 0; tm < 4; ++tm) {
        int rbase = wm * 64 + tm * 16 + q * 4;
#pragma unroll
        for (int i = 0; i < 4; ++i) {
            int row = m0 + rbase + i;
            if (row < M) {
                size_t hrow = (size_t)(sb + row) * H_DIM;
                ushort4v pk;
#pragma unroll
                for (int tn = 0; tn < 4; ++tn) {
                    float v = acc[tm][tn][i] + sBias[wn * 64 + tn * 16 + l4];
                    pk[tn] = f2b(gelu_fast(v));
                }
                *(ushort4v*)(hs + hrow + n0 + wn * 64 + l4 * 4) = pk;
            }
        }
    }
}

// ---------------- GEMM2 (split-K=2, BK=32): ybuf[kc][slot, perm(col)] = partial(h @ W2[e]) ----------------
__global__ __launch_bounds__(256) void gemm2_kernel(
    const __hip_bfloat16* __restrict__ hbuf, // [2T][H] (K-permuted, matches w2t)
    const __hip_bfloat16* __restrict__ w2t,  // [E][D][H] (B^T, K-permuted)
    const int* __restrict__ cnt, const int* __restrict__ base,
    __hip_bfloat16* __restrict__ ybuf,       // [2][2T][D] (N-permuted)
    int T) {
    int e = blockIdx.z >> 1;
    int kc = blockIdx.z & 1;
    int M = cnt[e];
    int m0 = blockIdx.y * 128;
    if (m0 >= M) return;
    int n0 = blockIdx.x * 128;
    int sb = base[e];
    const __hip_bfloat16* Bp = w2t + (size_t)e * D_DIM * H_DIM;

    __shared__ __align__(16) short sA[128 * 32];
    __shared__ __align__(16) short sB[128 * 32];
    char* sAc = (char*)sA; char* sBc = (char*)sB;

    int tid = threadIdx.x;
    int w = tid >> 6, lane = tid & 63;
    int wm = w >> 1, wn = w & 1;
    int q = lane >> 4, l4 = lane & 15;

    int kswz = ((lane & 3) ^ ((lane >> 3) & 3)) << 3;
    int r0 = w * 32 + (lane >> 2);
    int r1 = r0 + 16;
    const __hip_bfloat16* gA0 = hbuf + (size_t)(sb + min(m0 + r0, M - 1)) * H_DIM + kswz;
    const __hip_bfloat16* gA1 = hbuf + (size_t)(sb + min(m0 + r1, M - 1)) * H_DIM + kswz;
    const __hip_bfloat16* gB0 = Bp + (size_t)(n0 + r0) * H_DIM + kswz;
    const __hip_bfloat16* gB1 = Bp + (size_t)(n0 + r1) * H_DIM + kswz;
    char* lA0 = sAc + w * 2048 + lane * 16;
    char* lB0 = sBc + w * 2048 + lane * 16;
    char* lA1 = sAc + w * 2048 + 1024;
    char* lB1 = sBc + w * 2048 + 1024;

    f32x4 acc[4][4];
#pragma unroll
    for (int a = 0; a < 4; ++a)
#pragma unroll
        for (int b = 0; b < 4; ++b) acc[a][b] = (f32x4){0.f, 0.f, 0.f, 0.f};

    int k0 = kc * (H_DIM / 2), k1 = k0 + (H_DIM / 2);
    for (int kk = k0; kk < k1; kk += 32) {
        async_load16(gA0 + kk, lA0);
        async_load16(gA1 + kk, lA1);
        async_load16(gB0 + kk, lB0);
        async_load16(gB1 + kk, lB1);
        __syncthreads();
        short8 aF[4], bF[4];
#pragma unroll
        for (int t = 0; t < 4; ++t) {
            int ra = wm * 64 + t * 16 + l4;
            aF[t] = *(const short8*)(sAc + ra * 64 + ((q ^ ((ra >> 1) & 3)) << 4));
            int rb = wn * 64 + t * 16 + l4;
            bF[t] = *(const short8*)(sBc + rb * 64 + ((q ^ ((rb >> 1) & 3)) << 4));
        }
#pragma unroll
        for (int tm = 0; tm < 4; ++tm)
#pragma unroll
            for (int tn = 0; tn < 4; ++tn)
                acc[tm][tn] = __builtin_amdgcn_mfma_f32_16x16x32_bf16(aF[tm], bF[tn], acc[tm][tn], 0, 0, 0);
        __syncthreads();
    }

    size_t ybase = (size_t)kc * 2 * T;
    unsigned short* ys = (unsigned short*)ybuf;
#pragma unroll
    for (int tm = 0; tm < 4; ++tm) {
        int rbase = wm * 64 + tm * 16 + q * 4;
#pragma unroll
        for (int i = 0; i < 4; ++i) {
            int row = m0 + rbase + i;
            if (row < M) {
                size_t yrow = (ybase + sb + row) * D_DIM;
                ushort4v pk;
#pragma unroll
                for (int tn = 0; tn < 4; ++tn) pk[tn] = f2b(acc[tm][tn][i]);
                *(ushort4v*)(ys + yrow + n0 + wn * 64 + l4 * 4) = pk;
            }
        }
    }
}

// ---------------- combine: out[t, pi(c)] = sum_j w_j * (y_j(p0)+y_j(p1) + b2[e_j]) ----------------
__global__ __launch_bounds__(256) void combine_kernel(
    const __hip_bfloat16* __restrict__ yb, const float* __restrict__ b2,
    const int* __restrict__ base, const int* __restrict__ eidx,
    const float* __restrict__ ewgt, float* __restrict__ out, int T) {
    int t = blockIdx.x, tid = threadIdx.x;
    int v0 = eidx[2 * t], v1 = eidx[2 * t + 1];
    float w0 = ewgt[2 * t], w1 = ewgt[2 * t + 1];
    int e0 = v0 >> 16, e1 = v1 >> 16;
    size_t g0 = (size_t)base[e0] + (v0 & 0xffff);
    size_t g1 = (size_t)base[e1] + (v1 & 0xffff);
    int c = tid * 4;               // stored (permuted) col
    int blk = c >> 6;
    int tt = (c >> 2) & 15;
    size_t off2 = (size_t)2 * T * D_DIM;
    const short* ys = (const short*)yb;
    short4v a0 = *(const short4v*)(ys + g0 * D_DIM + c);
    short4v a1 = *(const short4v*)(ys + off2 + g0 * D_DIM + c);
    short4v c0 = *(const short4v*)(ys + g1 * D_DIM + c);
    short4v c1 = *(const short4v*)(ys + off2 + g1 * D_DIM + c);
    float s0[4] = { b2f(a0.x) + b2f(a1.x), b2f(a0.y) + b2f(a1.y),
                    b2f(a0.z) + b2f(a1.z), b2f(a0.w) + b2f(a1.w) };
    float s1[4] = { b2f(c0.x) + b2f(c1.x), b2f(c0.y) + b2f(c1.y),
                    b2f(c0.z) + b2f(c1.z), b2f(c0.w) + b2f(c1.w) };
    float* orow = out + (size_t)t * D_DIM;
#pragma unroll
    for (int s = 0; s < 4; ++s) {
        int oc = blk * 64 + s * 16 + tt;   // original col
        float o = w0 * (s0[s] + b2[(size_t)e0 * D_DIM + oc]) +
                  w1 * (s1[s] + b2[(size_t)e1 * D_DIM + oc]);
        orow[oc] = o;
    }
}

extern "C" void kernel_launch(void* const* d_in, const int* in_sizes, int n_in,
                              void* d_out, int out_size, void* d_ws, size_t ws_size,
                              hipStream_t stream) {
    const float* x  = (const float*)d_in[0];
    const float* Wg = (const float*)d_in[1];
    const float* W1 = (const float*)d_in[2];
    const float* b1 = (const float*)d_in[3];
    const float* W2 = (const float*)d_in[4];
    const float* b2 = (const float*)d_in[5];
    int T = in_sizes[0] / D_DIM;  // 8192

    char* p = (char*)d_ws;
    int* cnt   = (int*)p;
    int* base  = (int*)(p + 256);
    int* tok   = (int*)(p + 512);
    int* eidx  = (int*)(p + 512 + 4ll * E_NUM * T);
    float* ewgt = (float*)(p + 512 + 4ll * E_NUM * T + 8ll * T);
    int* epick = (int*)(p + 512 + 4ll * E_NUM * T + 16ll * T);
    char* pb = p + 512 + 4ll * E_NUM * T + 20ll * T;
    __hip_bfloat16* xb  = (__hip_bfloat16*)pb;
    __hip_bfloat16* w1t = xb + (size_t)T * D_DIM;
    __hip_bfloat16* w2t = w1t + (size_t)E_NUM * H_DIM * D_DIM;
    __hip_bfloat16* hb  = w2t + (size_t)E_NUM * H_DIM * D_DIM;
    // ybuf [2][2T][D] bf16 (67 MB) aliases xb+w1t (dead by gemm2 time).
    __hip_bfloat16* yb  = xb;

    hipMemsetAsync(cnt, 0, 256, stream);

    router_kernel<<<dim3((T + 3) / 4), 256, 0, stream>>>(x, Wg, xb, epick, ewgt, T);
    bucket_kernel<<<dim3(T / 128), 256, 0, stream>>>(epick, cnt, tok, eidx, T);
    prefix_kernel<<<1, 64, 0, stream>>>(cnt, base);
    transpose_both_kernel<<<dim3(2048, 1, E_NUM), dim3(32, 8), 0, stream>>>(W1, W2, w1t, w2t);
    gemm1_kernel<<<dim3(H_DIM / 128, T / 128, E_NUM), 256, 0, stream>>>(xb, w1t, b1, cnt, base, tok, hb, T);
    gemm2_kernel<<<dim3(D_DIM / 128, T / 128, E_NUM * 2), 256, 0, stream>>>(hb, w2t, cnt, base, yb, T);
    combine_kernel<<<T, 256, 0, stream>>>(yb, b2, base, eidx, ewgt, (float*)d_out, T);
}